// Round 1
// baseline (563.351 us; speedup 1.0000x reference)
//
#include <hip/hip_runtime.h>
#include <hip/hip_bf16.h>
#include <stdint.h>

#define DEV __device__ __forceinline__

constexpr int BATCH = 2048;
constexpr int INF   = 2048;
constexpr int T     = 2045;   // L
constexpr int Tp    = 2056;   // padded T for LSTM prefetch overrun
constexpr int HID   = 512;    // FC_HID
constexpr int OUTF  = 720;
constexpr int KFp   = 8192;   // padded flat width (8180 -> 8192)

typedef __bf16 bf16x8 __attribute__((ext_vector_type(8)));
typedef float  f32x4  __attribute__((ext_vector_type(4)));

// ---- workspace layout (bytes) ----
constexpr size_t OFF_Y1   = 0;                              // f32 [2048][2056][4]   = 67,371,008
constexpr size_t OFF_HBUF = 67371008;                       // bf16 [2048][2045][4]  = 33,505,280
constexpr size_t OFF_FLAT = 100876288;                      // bf16 [2048][8192]     = 33,554,432
constexpr size_t OFF_W1T  = 134430720;                      // bf16 [512][8192]      =  8,388,608
constexpr size_t OFF_W2T  = 142819328;                      // bf16 [768][512]       =    786,432
constexpr size_t OFF_PART = 143605760;                      // f32 [4][2048][512]    = 16,777,216
constexpr size_t OFF_ACT  = 160382976;                      // bf16 [2048][512]      =  2,097,152
constexpr size_t OFF_GS   = 162480128;                      // f32 [4][2048]         =     32,768
constexpr size_t OFF_AB   = 162512896;                      // float2 [2][2048]      =     32,768

DEV float fexp2(float x){ return __builtin_amdgcn_exp2f(x); }
DEV float frcp (float x){ return __builtin_amdgcn_rcpf(x); }
DEV float blo(unsigned u){ return __uint_as_float(u << 16); }
DEV float bhi(unsigned u){ return __uint_as_float(u & 0xffff0000u); }
DEV unsigned packbf(float lo, float hi){   // RNE pack of 2 bf16
  unsigned a = __float_as_uint(lo), b = __float_as_uint(hi);
  a = (a + 0x7fffu + ((a >> 16) & 1u)) >> 16;
  b = (b + 0x7fffu + ((b >> 16) & 1u)) & 0xffff0000u;
  return a | b;
}

// exact gelu via Abramowitz-Stegun erf (|err| < 1.5e-7)
DEV float gelu_f(float x){
  const float L2E = 1.4426950408889634f;
  float z  = x * 0.70710678118654752f;
  float az = fabsf(z);
  float t  = frcp(fmaf(0.3275911f, az, 1.0f));
  float p  = fmaf(1.061405429f, t, -1.453152027f);
  p = fmaf(p, t,  1.421413741f);
  p = fmaf(p, t, -0.284496736f);
  p = fmaf(p, t,  0.254829592f);
  float e = fexp2(-az * az * L2E);
  float erf_abs = fmaf(-p * t, e, 1.0f);
  float erf = (z < 0.f) ? -erf_abs : erf_abs;
  return 0.5f * x * (1.0f + erf);
}

// ---------------- K1: patches -> 4x4 matmul -> gelu -> y1 ; bn1 partial sums ----
__global__ __launch_bounds__(256) void k_stageA(
    const float* __restrict__ x, const float* __restrict__ pe,
    const float* __restrict__ w_seg, const float* __restrict__ b_seg,
    float* __restrict__ y1, float* __restrict__ gs1, float* __restrict__ gs1b)
{
  __shared__ float red[4][64][2];
  const int tx = threadIdx.x & 63;
  const int wv = threadIdx.x >> 6;
  const int t  = blockIdx.x * 64 + tx;
  const int b0 = blockIdx.y * 16 + wv * 4;

  float ws[4][4], bs[4];
  #pragma unroll
  for (int j = 0; j < 4; j++){
    bs[j] = b_seg[j];
    #pragma unroll
    for (int k = 0; k < 4; k++) ws[j][k] = w_seg[j*4 + k];
  }
  const bool valid = (t < T);
  float pe0=0, pe1=0, pe2=0, pe3=0;
  if (valid){
    const float4 p4 = *(const float4*)(pe + (size_t)t*4);
    pe0=p4.x; pe1=p4.y; pe2=p4.z; pe3=p4.w;
  }
  float s = 0.f, s2 = 0.f;
  if (valid){
    #pragma unroll
    for (int bb = 0; bb < 4; bb++){
      const int b = b0 + bb;
      const float* xr = x + (size_t)b*INF + t;
      const float x0 = xr[0]+pe0, x1 = xr[1]+pe1, x2 = xr[2]+pe2, x3 = xr[3]+pe3;
      float4 o;
      float* op = &o.x;
      #pragma unroll
      for (int j = 0; j < 4; j++){
        float v = fmaf(x0,ws[j][0], fmaf(x1,ws[j][1], fmaf(x2,ws[j][2], fmaf(x3,ws[j][3], bs[j]))));
        v = gelu_f(v);
        op[j] = v;
        s += v; s2 += v*v;
      }
      *(float4*)(y1 + ((size_t)b*Tp + t)*4) = o;
    }
  }
  red[wv][tx][0] = s; red[wv][tx][1] = s2;
  __syncthreads();
  if (wv == 0 && valid){
    float S  = red[0][tx][0]+red[1][tx][0]+red[2][tx][0]+red[3][tx][0];
    float S2 = red[0][tx][1]+red[1][tx][1]+red[2][tx][1]+red[3][tx][1];
    atomicAdd(&gs1[t],  S);
    atomicAdd(&gs1b[t], S2);
  }
}

// ---------------- K2: bn finalize -> (a, b') per channel t ----------------------
__global__ __launch_bounds__(256) void k_bnfin(
    const float* __restrict__ gsum, const float* __restrict__ gsum2,
    const float* __restrict__ g, const float* __restrict__ bparm, float2* __restrict__ ab)
{
  const int t = blockIdx.x * 256 + threadIdx.x;
  if (t >= T) return;
  const float invN = 1.0f / 8192.0f;
  const float m = gsum[t] * invN;
  const float v = gsum2[t] * invN - m*m;
  const float a = g[t] * rsqrtf(v + 1e-5f);
  ab[t] = make_float2(a, bparm[t] - m*a);
}

// ---------------- K3: LSTM, 16 lanes per row, bn1 folded into W_ih dot ----------
__global__ __launch_bounds__(64) void k_lstm(
    const float* __restrict__ y1, const float2* __restrict__ ab1,
    const float* __restrict__ w_ih, const float* __restrict__ w_hh,
    __hip_bfloat16* __restrict__ hbuf)
{
  const int lane = threadIdx.x;          // 0..63, 4 rows x 16 gates
  const int g16  = lane & 15;            // gate index 0..15 (i0-3,f0-3,g0-3,o0-3)
  const int jj   = lane & 3;             // unit index
  const int b    = blockIdx.x * 4 + (lane >> 4);

  const float wx0 = w_ih[g16*4+0], wx1 = w_ih[g16*4+1], wx2 = w_ih[g16*4+2], wx3 = w_ih[g16*4+3];
  const float wh0 = w_hh[g16*4+0], wh1 = w_hh[g16*4+1], wh2 = w_hh[g16*4+2], wh3 = w_hh[g16*4+3];
  const float rsW = wx0 + wx1 + wx2 + wx3;
  const int ty = g16 >> 2;               // 0=i 1=f 2=g 3=o
  const float L2E = 1.4426950408889634f;
  const float sc = (ty == 2) ? -2.f*L2E : -L2E;   // exp2 scale: sigmoid vs tanh
  const float aA = (ty == 2) ? 2.f : 1.f;
  const float aB = (ty == 2) ? -1.f : 0.f;

  const int base16 = lane & ~15;
  const int a_i = (base16 + jj) << 2;
  const int a_f = (base16 + 4  + jj) << 2;
  const int a_g = (base16 + 8  + jj) << 2;
  const int a_o = (base16 + 12 + jj) << 2;
  const int qb = lane & ~3;
  const int a_h0 = qb << 2, a_h1 = (qb+1) << 2, a_h2 = (qb+2) << 2, a_h3 = (qb+3) << 2;

  const float4* yrow = (const float4*)(y1 + (size_t)b*Tp*4);
  __hip_bfloat16* hrow = hbuf + (size_t)b*T*4 + jj;

  float h0=0.f, h1=0.f, h2=0.f, h3=0.f, c=0.f;

  auto step = [&](int t, float4 y){
    float2 abv = ab1[t];
    float d = fmaf(y.x, wx0, fmaf(y.y, wx1, fmaf(y.z, wx2, y.w * wx3)));
    float gt = fmaf(d, abv.x, rsW * abv.y);                 // bn1 folded
    gt = fmaf(h0, wh0, fmaf(h1, wh1, fmaf(h2, wh2, fmaf(h3, wh3, gt))));
    float act = fmaf(aA, frcp(1.f + fexp2(sc * gt)), aB);   // sigmoid or tanh per lane
    int ia = __float_as_int(act);
    float vi = __int_as_float(__builtin_amdgcn_ds_bpermute(a_i, ia));
    float vf = __int_as_float(__builtin_amdgcn_ds_bpermute(a_f, ia));
    float vg = __int_as_float(__builtin_amdgcn_ds_bpermute(a_g, ia));
    float vo = __int_as_float(__builtin_amdgcn_ds_bpermute(a_o, ia));
    c = fmaf(vf, c, vi * vg);
    float tc = fmaf(2.f, frcp(1.f + fexp2(-2.f*L2E * c)), -1.f);
    float hj = vo * tc;
    int ih = __float_as_int(hj);
    h0 = __int_as_float(__builtin_amdgcn_ds_bpermute(a_h0, ih));
    h1 = __int_as_float(__builtin_amdgcn_ds_bpermute(a_h1, ih));
    h2 = __int_as_float(__builtin_amdgcn_ds_bpermute(a_h2, ih));
    h3 = __int_as_float(__builtin_amdgcn_ds_bpermute(a_h3, ih));
    if (g16 < 4) hrow[(size_t)t*4] = __float2bfloat16(hj);
  };

  float4 buf[8];
  #pragma unroll
  for (int u = 0; u < 8; u++) buf[u] = yrow[u];

  for (int t0 = 0; t0 < T-5; t0 += 8){        // t0 = 0..2032, covers t<2040
    #pragma unroll
    for (int u = 0; u < 8; u++){
      float4 y = buf[u];
      buf[u] = yrow[t0 + u + 8];              // prefetch (padded to Tp)
      step(t0 + u, y);
    }
  }
  #pragma unroll
  for (int u = 0; u < 5; u++) step(2040 + u, buf[u]);   // tail t=2040..2044
}

// ---------------- K4: bn2 partial sums over h (per-t bins in LDS) ---------------
__global__ __launch_bounds__(256) void k_bn2red(
    const __hip_bfloat16* __restrict__ hbuf, float* __restrict__ gsum, float* __restrict__ gsum2)
{
  __shared__ float ls[2048];
  __shared__ float ls2[2048];
  for (int i = threadIdx.x; i < 2048; i += 256){ ls[i] = 0.f; ls2[i] = 0.f; }
  __syncthreads();
  const int lane = threadIdx.x & 63;
  const int wv = threadIdx.x >> 6;
  const int r = blockIdx.x*16 + wv*4 + (lane >> 4);
  const int tx = lane & 15;
  const __hip_bfloat16* hrow = hbuf + (size_t)r*T*4;
  for (int p = tx; p < 1022; p += 16){
    uint2 va = *(const uint2*)(hrow + (size_t)p*8);
    uint2 vb = *(const uint2*)(hrow + (size_t)p*8 + 4);
    float a0=blo(va.x),a1=bhi(va.x),a2=blo(va.y),a3=bhi(va.y);
    float b0=blo(vb.x),b1=bhi(vb.x),b2=blo(vb.y),b3=bhi(vb.y);
    atomicAdd(&ls [2*p    ], a0+a1+a2+a3);
    atomicAdd(&ls2[2*p    ], a0*a0+a1*a1+a2*a2+a3*a3);
    atomicAdd(&ls [2*p + 1], b0+b1+b2+b3);
    atomicAdd(&ls2[2*p + 1], b0*b0+b1*b1+b2*b2+b3*b3);
  }
  if (tx == 0){  // tail t = 2044
    uint2 va = *(const uint2*)(hrow + (size_t)2044*4);
    float a0=blo(va.x),a1=bhi(va.x),a2=blo(va.y),a3=bhi(va.y);
    atomicAdd(&ls [2044], a0+a1+a2+a3);
    atomicAdd(&ls2[2044], a0*a0+a1*a1+a2*a2+a3*a3);
  }
  __syncthreads();
  for (int i = threadIdx.x; i < T; i += 256){
    atomicAdd(&gsum[i],  ls[i]);
    atomicAdd(&gsum2[i], ls2[i]);
  }
}

// ---------------- K5: fuse bn2(h) + bn1(y1) -> flat bf16 (padded 8192) ----------
__global__ __launch_bounds__(256) void k_fuse(
    const __hip_bfloat16* __restrict__ hbuf, const float* __restrict__ y1,
    const float2* __restrict__ ab1, const float2* __restrict__ ab2,
    __hip_bfloat16* __restrict__ flat)
{
  const int idx = blockIdx.x*256 + threadIdx.x;   // 2048 rows * 1024 pairs
  const int r = idx >> 10;
  const int p = idx & 1023;
  unsigned w[4];
  #pragma unroll
  for (int hv = 0; hv < 2; hv++){
    const int t = 2*p + hv;
    float v0, v1, v2, v3;
    if (t < T){
      uint2 hh = *(const uint2*)(hbuf + ((size_t)r*T + t)*4);
      float4 yy = *(const float4*)(y1 + ((size_t)r*Tp + t)*4);
      float2 A1 = ab1[t];
      float2 A2 = ab2[t];
      v0 = fmaf(blo(hh.x), A2.x, A2.y) + fmaf(yy.x, A1.x, A1.y);
      v1 = fmaf(bhi(hh.x), A2.x, A2.y) + fmaf(yy.y, A1.x, A1.y);
      v2 = fmaf(blo(hh.y), A2.x, A2.y) + fmaf(yy.z, A1.x, A1.y);
      v3 = fmaf(bhi(hh.y), A2.x, A2.y) + fmaf(yy.w, A1.x, A1.y);
    } else { v0=v1=v2=v3=0.f; }
    w[hv*2+0] = packbf(v0, v1);
    w[hv*2+1] = packbf(v2, v3);
  }
  uint4 o4 = make_uint4(w[0], w[1], w[2], w[3]);
  *(uint4*)(flat + ((size_t)r*KFp + ((size_t)p << 3))) = o4;
}

// ---------------- K6: fp32 KxN -> bf16 NpxKp transpose (zero-padded) ------------
__global__ __launch_bounds__(256) void k_transpose(
    const float* __restrict__ src, __hip_bfloat16* __restrict__ dst,
    int K, int N, int Kp, int Np)
{
  __shared__ float tile[32][33];
  const int k0 = blockIdx.x*32, n0 = blockIdx.y*32;
  const int tx = threadIdx.x & 31, tyv = threadIdx.x >> 5;
  #pragma unroll
  for (int q = 0; q < 4; q++){
    int k = k0 + tyv + q*8, n = n0 + tx;
    tile[tyv + q*8][tx] = (k < K && n < N) ? src[(size_t)k*N + n] : 0.f;
  }
  __syncthreads();
  #pragma unroll
  for (int q = 0; q < 4; q++){
    int n = n0 + tyv + q*8, k = k0 + tx;
    dst[(size_t)n*Kp + k] = __float2bfloat16(tile[tx][tyv + q*8]);
  }
}

// ---------------- K7: bf16 MFMA GEMM (A row-major MxK, B as [n][k]) -------------
#define AS1 __attribute__((address_space(1)))
#define AS3 __attribute__((address_space(3)))
__global__ __launch_bounds__(256) void k_gemm(
    const __hip_bfloat16* __restrict__ A, int lda,
    const __hip_bfloat16* __restrict__ Bm, int ldb,
    int Klen, float* __restrict__ Cb, size_t csplit, int ldc,
    int nvalid, const float* __restrict__ bias, int epi)
{
  __shared__ __hip_bfloat16 As[4096];   // [128][32]
  __shared__ __hip_bfloat16 Bs[4096];   // [128][32]
  const int tid = threadIdx.x;
  const int lane = tid & 63;
  const int wv = tid >> 6;
  const int M0 = blockIdx.x * 128;
  const int N0 = blockIdx.y * 128;
  const int Kstart = blockIdx.z * Klen;
  float* C = Cb + (size_t)blockIdx.z * csplit;

  const int s0 = wv*64 + lane;
  const int arow = s0 >> 2, aseg = (s0 & 3) * 8;
  const __hip_bfloat16* gA0 = A  + (size_t)(M0 + arow)      * lda + Kstart + aseg;
  const __hip_bfloat16* gA1 = A  + (size_t)(M0 + arow + 64) * lda + Kstart + aseg;
  const __hip_bfloat16* gB0 = Bm + (size_t)(N0 + arow)      * ldb + Kstart + aseg;
  const __hip_bfloat16* gB1 = Bm + (size_t)(N0 + arow + 64) * ldb + Kstart + aseg;
  char* dA0 = (char*)As + wv*1024;
  char* dA1 = (char*)As + 4096 + wv*1024;
  char* dB0 = (char*)Bs + wv*1024;
  char* dB1 = (char*)Bs + 4096 + wv*1024;

  const int wm = (wv & 1) * 64;
  const int wn = (wv >> 1) * 64;
  const int lr = lane & 15;
  const int lk = lane >> 4;

  f32x4 acc[4][4] = {};

  for (int kk = 0; kk < Klen; kk += 32){
    __builtin_amdgcn_global_load_lds((const AS1 void*)gA0, (AS3 void*)dA0, 16, 0, 0);
    __builtin_amdgcn_global_load_lds((const AS1 void*)gA1, (AS3 void*)dA1, 16, 0, 0);
    __builtin_amdgcn_global_load_lds((const AS1 void*)gB0, (AS3 void*)dB0, 16, 0, 0);
    __builtin_amdgcn_global_load_lds((const AS1 void*)gB1, (AS3 void*)dB1, 16, 0, 0);
    gA0 += 32; gA1 += 32; gB0 += 32; gB1 += 32;
    __syncthreads();
    bf16x8 af[4], bfr[4];
    #pragma unroll
    for (int mi = 0; mi < 4; mi++)
      af[mi] = *(const bf16x8*)((char*)As + (wm + mi*16 + lr)*64 + lk*16);
    #pragma unroll
    for (int ni = 0; ni < 4; ni++)
      bfr[ni] = *(const bf16x8*)((char*)Bs + (wn + ni*16 + lr)*64 + lk*16);
    #pragma unroll
    for (int mi = 0; mi < 4; mi++)
      #pragma unroll
      for (int ni = 0; ni < 4; ni++)
        acc[mi][ni] = __builtin_amdgcn_mfma_f32_16x16x32_bf16(af[mi], bfr[ni], acc[mi][ni], 0, 0, 0);
    __syncthreads();
  }

  #pragma unroll
  for (int mi = 0; mi < 4; mi++){
    #pragma unroll
    for (int ni = 0; ni < 4; ni++){
      const int row = M0 + wm + mi*16 + lk*4;
      const int col = N0 + wn + ni*16 + lr;
      if (epi == 0){
        float* cp = C + (size_t)row*ldc + col;
        #pragma unroll
        for (int q = 0; q < 4; q++) cp[(size_t)q*ldc] = acc[mi][ni][q];
      } else if (col < nvalid){
        const float bz = bias[col];
        float* cp = C + (size_t)row*ldc + col;
        #pragma unroll
        for (int q = 0; q < 4; q++) cp[(size_t)q*ldc] = acc[mi][ni][q] + bz;
      }
    }
  }
}

// ---------------- K8: combine split-K partials + bias + gelu -> act bf16 --------
__global__ __launch_bounds__(256) void k_comb(
    const float* __restrict__ part, const float* __restrict__ b_fc1,
    __hip_bfloat16* __restrict__ act)
{
  const int idx = blockIdx.x*256 + threadIdx.x;   // 2048*128
  const int m = idx >> 7;
  const int n = (idx & 127) << 2;
  const size_t o = (size_t)m*HID + n;
  const size_t S = (size_t)2048*HID;
  float4 p0 = *(const float4*)(part + o);
  float4 p1 = *(const float4*)(part + S + o);
  float4 p2 = *(const float4*)(part + 2*S + o);
  float4 p3 = *(const float4*)(part + 3*S + o);
  float4 bz = *(const float4*)(b_fc1 + n);
  float v0 = gelu_f(p0.x+p1.x+p2.x+p3.x+bz.x);
  float v1 = gelu_f(p0.y+p1.y+p2.y+p3.y+bz.y);
  float v2 = gelu_f(p0.z+p1.z+p2.z+p3.z+bz.z);
  float v3 = gelu_f(p0.w+p1.w+p2.w+p3.w+bz.w);
  uint2 pk; pk.x = packbf(v0, v1); pk.y = packbf(v2, v3);
  *(uint2*)(act + o) = pk;
}

// ---------------- launch --------------------------------------------------------
extern "C" void kernel_launch(void* const* d_in, const int* in_sizes, int n_in,
                              void* d_out, int out_size, void* d_ws, size_t ws_size,
                              hipStream_t stream)
{
  (void)in_sizes; (void)n_in; (void)out_size; (void)ws_size;
  const float* x     = (const float*)d_in[0];
  const float* pe    = (const float*)d_in[1];
  const float* w_seg = (const float*)d_in[2];
  const float* b_seg = (const float*)d_in[3];
  const float* bn1_g = (const float*)d_in[4];
  const float* bn1_b = (const float*)d_in[5];
  const float* w_ih  = (const float*)d_in[6];
  const float* w_hh  = (const float*)d_in[7];
  const float* bn2_g = (const float*)d_in[8];
  const float* bn2_b = (const float*)d_in[9];
  const float* w_fc1 = (const float*)d_in[10];
  const float* b_fc1 = (const float*)d_in[11];
  const float* w_fc2 = (const float*)d_in[12];
  const float* b_fc2 = (const float*)d_in[13];
  float* out = (float*)d_out;

  char* ws = (char*)d_ws;
  float* y1            = (float*)(ws + OFF_Y1);
  __hip_bfloat16* hbuf = (__hip_bfloat16*)(ws + OFF_HBUF);
  __hip_bfloat16* flat = (__hip_bfloat16*)(ws + OFF_FLAT);
  __hip_bfloat16* w1t  = (__hip_bfloat16*)(ws + OFF_W1T);
  __hip_bfloat16* w2t  = (__hip_bfloat16*)(ws + OFF_W2T);
  float* part          = (float*)(ws + OFF_PART);
  __hip_bfloat16* act  = (__hip_bfloat16*)(ws + OFF_ACT);
  float* gs            = (float*)(ws + OFF_GS);
  float2* ab1          = (float2*)(ws + OFF_AB);
  float2* ab2          = ab1 + 2048;

  hipMemsetAsync(gs, 0, 4*2048*sizeof(float), stream);

  k_stageA<<<dim3(32,128), 256, 0, stream>>>(x, pe, w_seg, b_seg, y1, gs, gs + 2048);
  k_bnfin <<<8, 256, 0, stream>>>(gs, gs + 2048, bn1_g, bn1_b, ab1);
  k_lstm  <<<512, 64, 0, stream>>>(y1, ab1, w_ih, w_hh, hbuf);
  k_bn2red<<<128, 256, 0, stream>>>(hbuf, gs + 4096, gs + 6144);
  k_bnfin <<<8, 256, 0, stream>>>(gs + 4096, gs + 6144, bn2_g, bn2_b, ab2);
  k_transpose<<<dim3(256,16), 256, 0, stream>>>(w_fc1, w1t, 8180, 512, 8192, 512);
  k_transpose<<<dim3(16,24),  256, 0, stream>>>(w_fc2, w2t, 512, 720, 512, 768);
  k_fuse  <<<8192, 256, 0, stream>>>(hbuf, y1, ab1, ab2, flat);
  k_gemm  <<<dim3(16,4,4), 256, 0, stream>>>(flat, 8192, w1t, 8192, 2048,
                                             part, (size_t)2048*512, 512, 512, nullptr, 0);
  k_comb  <<<1024, 256, 0, stream>>>(part, b_fc1, act);
  k_gemm  <<<dim3(16,6,1), 256, 0, stream>>>(act, 512, w2t, 512, 512,
                                             out, 0, 720, 720, b_fc2, 1);
}

// Round 2
// 450.589 us; speedup vs baseline: 1.2503x; 1.2503x over previous
//
#include <hip/hip_runtime.h>
#include <hip/hip_bf16.h>
#include <stdint.h>

#define DEV __device__ __forceinline__

constexpr int BATCH = 2048;
constexpr int INF   = 2048;
constexpr int T     = 2045;   // L
constexpr int Tp    = 2056;   // padded T for LSTM prefetch overrun
constexpr int HID   = 512;    // FC_HID
constexpr int OUTF  = 720;
constexpr int KFp   = 8192;   // padded flat width (8180 -> 8192)

typedef __bf16 bf16x8 __attribute__((ext_vector_type(8)));
typedef float  f32x4  __attribute__((ext_vector_type(4)));

// ---- workspace layout (bytes) ----
constexpr size_t OFF_Y1   = 0;                              // f32 [2048][2056][4]   = 67,371,008
constexpr size_t OFF_HBUF = 67371008;                       // bf16 [2048][2045][4]  = 33,505,280
constexpr size_t OFF_FLAT = 100876288;                      // bf16 [2048][8192]     = 33,554,432
constexpr size_t OFF_W1T  = 134430720;                      // bf16 [512][8192]      =  8,388,608
constexpr size_t OFF_W2T  = 142819328;                      // bf16 [768][512]       =    786,432
constexpr size_t OFF_PART = 143605760;                      // f32 [4][2048][512]    = 16,777,216
constexpr size_t OFF_ACT  = 160382976;                      // bf16 [2048][512]      =  2,097,152
constexpr size_t OFF_GS   = 162480128;                      // f32 [4][2048]         =     32,768
constexpr size_t OFF_AB   = 162512896;                      // float2 [2][2048]      =     32,768

DEV float fexp2(float x){ return __builtin_amdgcn_exp2f(x); }
DEV float frcp (float x){ return __builtin_amdgcn_rcpf(x); }
DEV float blo(unsigned u){ return __uint_as_float(u << 16); }
DEV float bhi(unsigned u){ return __uint_as_float(u & 0xffff0000u); }
DEV unsigned packbf(float lo, float hi){   // RNE pack of 2 bf16
  unsigned a = __float_as_uint(lo), b = __float_as_uint(hi);
  a = (a + 0x7fffu + ((a >> 16) & 1u)) >> 16;
  b = (b + 0x7fffu + ((b >> 16) & 1u)) & 0xffff0000u;
  return a | b;
}

// exact gelu via Abramowitz-Stegun erf (|err| < 1.5e-7)
DEV float gelu_f(float x){
  const float L2E = 1.4426950408889634f;
  float z  = x * 0.70710678118654752f;
  float az = fabsf(z);
  float t  = frcp(fmaf(0.3275911f, az, 1.0f));
  float p  = fmaf(1.061405429f, t, -1.453152027f);
  p = fmaf(p, t,  1.421413741f);
  p = fmaf(p, t, -0.284496736f);
  p = fmaf(p, t,  0.254829592f);
  float e = fexp2(-az * az * L2E);
  float erf_abs = fmaf(-p * t, e, 1.0f);
  float erf = (z < 0.f) ? -erf_abs : erf_abs;
  return 0.5f * x * (1.0f + erf);
}

// ---------------- K1: patches -> 4x4 matmul -> gelu -> y1 ; bn1 partial sums ----
__global__ __launch_bounds__(256) void k_stageA(
    const float* __restrict__ x, const float* __restrict__ pe,
    const float* __restrict__ w_seg, const float* __restrict__ b_seg,
    float* __restrict__ y1, float* __restrict__ gs1, float* __restrict__ gs1b)
{
  __shared__ float red[4][64][2];
  const int tx = threadIdx.x & 63;
  const int wv = threadIdx.x >> 6;
  const int t  = blockIdx.x * 64 + tx;
  const int b0 = blockIdx.y * 16 + wv * 4;

  float ws[4][4], bs[4];
  #pragma unroll
  for (int j = 0; j < 4; j++){
    bs[j] = b_seg[j];
    #pragma unroll
    for (int k = 0; k < 4; k++) ws[j][k] = w_seg[j*4 + k];
  }
  const bool valid = (t < T);
  float pe0=0, pe1=0, pe2=0, pe3=0;
  if (valid){
    const float4 p4 = *(const float4*)(pe + (size_t)t*4);
    pe0=p4.x; pe1=p4.y; pe2=p4.z; pe3=p4.w;
  }
  float s = 0.f, s2 = 0.f;
  if (valid){
    #pragma unroll
    for (int bb = 0; bb < 4; bb++){
      const int b = b0 + bb;
      const float* xr = x + (size_t)b*INF + t;
      const float x0 = xr[0]+pe0, x1 = xr[1]+pe1, x2 = xr[2]+pe2, x3 = xr[3]+pe3;
      float4 o;
      float* op = &o.x;
      #pragma unroll
      for (int j = 0; j < 4; j++){
        float v = fmaf(x0,ws[j][0], fmaf(x1,ws[j][1], fmaf(x2,ws[j][2], fmaf(x3,ws[j][3], bs[j]))));
        v = gelu_f(v);
        op[j] = v;
        s += v; s2 += v*v;
      }
      *(float4*)(y1 + ((size_t)b*Tp + t)*4) = o;
    }
  }
  red[wv][tx][0] = s; red[wv][tx][1] = s2;
  __syncthreads();
  if (wv == 0 && valid){
    float S  = red[0][tx][0]+red[1][tx][0]+red[2][tx][0]+red[3][tx][0];
    float S2 = red[0][tx][1]+red[1][tx][1]+red[2][tx][1]+red[3][tx][1];
    atomicAdd(&gs1[t],  S);
    atomicAdd(&gs1b[t], S2);
  }
}

// ---------------- K2: bn finalize -> (a, b') per channel t ----------------------
__global__ __launch_bounds__(256) void k_bnfin(
    const float* __restrict__ gsum, const float* __restrict__ gsum2,
    const float* __restrict__ g, const float* __restrict__ bparm, float2* __restrict__ ab)
{
  const int t = blockIdx.x * 256 + threadIdx.x;
  if (t >= T) return;
  const float invN = 1.0f / 8192.0f;
  const float m = gsum[t] * invN;
  const float v = gsum2[t] * invN - m*m;
  const float a = g[t] * rsqrtf(v + 1e-5f);
  ab[t] = make_float2(a, bparm[t] - m*a);
}

// ---------------- K3: LSTM — unit-major lanes, DPP-only cross-lane --------------
// lane16 = 4*u + q (u = hidden unit, q = gate type 0=i 1=f 2=g 3=o).
// Cell exchange (i,f,g,o of unit u) = quad_perm broadcasts (VALU-speed).
// h-dot across units = 4-stage row_ror:4 ring fused into the W_hh dot.
DEV float rot4f(float x){
  return __int_as_float(__builtin_amdgcn_update_dpp(
      0, __float_as_int(x), 0x124 /*row_ror:4*/, 0xF, 0xF, true));
}
DEV float qperm(float x, int ctrl){
  switch (ctrl){   // ctrl must be an immediate
    case 0x00: return __int_as_float(__builtin_amdgcn_update_dpp(0, __float_as_int(x), 0x00, 0xF, 0xF, true));
    case 0x55: return __int_as_float(__builtin_amdgcn_update_dpp(0, __float_as_int(x), 0x55, 0xF, 0xF, true));
    case 0xAA: return __int_as_float(__builtin_amdgcn_update_dpp(0, __float_as_int(x), 0xAA, 0xF, 0xF, true));
    default:   return __int_as_float(__builtin_amdgcn_update_dpp(0, __float_as_int(x), 0xFF, 0xF, 0xF, true));
  }
}

__global__ __launch_bounds__(64) void k_lstm(
    const float* __restrict__ y1, const float2* __restrict__ ab1,
    const float* __restrict__ w_ih, const float* __restrict__ w_hh,
    __hip_bfloat16* __restrict__ hbuf)
{
  const int lane = threadIdx.x;          // 0..63 = 4 rows x 16 lanes
  const int l16  = lane & 15;
  const int u    = l16 >> 2;             // hidden unit 0..3
  const int q    = l16 & 3;              // gate type: 0=i 1=f 2=g 3=o
  const int g    = q*4 + u;              // row in w_ih / w_hh
  const int b    = blockIdx.x * 4 + (lane >> 4);

  const float L2E = 1.4426950408889634f;
  const float sc = (q == 2) ? -2.f*L2E : -L2E;    // pre-scale for exp2-based act
  const float aA = (q == 2) ? 2.f : 1.f;
  const float aB = (q == 2) ? -1.f : 0.f;

  // pre-scaled input weights (bn1 'a' multiplies d; 'b' multiplies row-sum)
  const float wx0 = w_ih[g*4+0]*sc, wx1 = w_ih[g*4+1]*sc,
              wx2 = w_ih[g*4+2]*sc, wx3 = w_ih[g*4+3]*sc;
  const float rsW = wx0 + wx1 + wx2 + wx3;

  // Direction-agnostic ring weights: rotate an index with the SAME dpp op,
  // then fetch W_hh columns in exactly the order the hardware rotates h.
  int uidx = u;
  float whr0 = w_hh[g*4 + uidx] * sc;
  uidx = __builtin_amdgcn_update_dpp(0, uidx, 0x124, 0xF, 0xF, true);
  float whr1 = w_hh[g*4 + uidx] * sc;
  uidx = __builtin_amdgcn_update_dpp(0, uidx, 0x124, 0xF, 0xF, true);
  float whr2 = w_hh[g*4 + uidx] * sc;
  uidx = __builtin_amdgcn_update_dpp(0, uidx, 0x124, 0xF, 0xF, true);
  float whr3 = w_hh[g*4 + uidx] * sc;

  const float4* yrow = (const float4*)(y1 + (size_t)b*Tp*4);
  __hip_bfloat16* hrow = hbuf + (size_t)b*T*4 + u;

  float h = 0.f, c = 0.f;

  auto step = [&](int t, float4 y, float2 abv){
    float d  = fmaf(y.x,wx0, fmaf(y.y,wx1, fmaf(y.z,wx2, y.w*wx3)));
    float gx = fmaf(d, abv.x, rsW * abv.y);          // bn1 folded, pre-scaled
    float gt = fmaf(h, whr0, gx);                    // h-dot ring (row_ror:4)
    float hr = rot4f(h);
    gt = fmaf(hr, whr1, gt);
    hr = rot4f(hr);
    gt = fmaf(hr, whr2, gt);
    hr = rot4f(hr);
    gt = fmaf(hr, whr3, gt);
    float act = fmaf(aA, frcp(1.f + fexp2(gt)), aB); // sigmoid / tanh per lane
    float vi = qperm(act, 0x00);
    float vf = qperm(act, 0x55);
    float vg = qperm(act, 0xAA);
    float vo = qperm(act, 0xFF);
    c = fmaf(vf, c, vi * vg);
    float tc = fmaf(2.f, frcp(1.f + fexp2(-2.f*L2E * c)), -1.f);
    h = vo * tc;
    if (q == 0) hrow[(size_t)t*4] = __float2bfloat16(h);
  };

  float4 buf[8]; float2 abuf[8];
  #pragma unroll
  for (int i = 0; i < 8; i++){ buf[i] = yrow[i]; abuf[i] = ab1[i]; }

  for (int t0 = 0; t0 < T-5; t0 += 8){        // t0 = 0..2032, covers t<2040
    #pragma unroll
    for (int v = 0; v < 8; v++){
      float4 y = buf[v]; float2 a2 = abuf[v];
      buf[v]  = yrow[t0 + v + 8];             // prefetch (y1 padded to Tp)
      abuf[v] = ab1[t0 + v + 8];              // max index 2047 < 2048
      step(t0 + v, y, a2);
    }
  }
  #pragma unroll
  for (int v = 0; v < 5; v++) step(2040 + v, buf[v], abuf[v]);   // t=2040..2044
}

// ---------------- K4: bn2 partial sums over h (per-t bins in LDS) ---------------
__global__ __launch_bounds__(256) void k_bn2red(
    const __hip_bfloat16* __restrict__ hbuf, float* __restrict__ gsum, float* __restrict__ gsum2)
{
  __shared__ float ls[2048];
  __shared__ float ls2[2048];
  for (int i = threadIdx.x; i < 2048; i += 256){ ls[i] = 0.f; ls2[i] = 0.f; }
  __syncthreads();
  const int lane = threadIdx.x & 63;
  const int wv = threadIdx.x >> 6;
  const int r = blockIdx.x*16 + wv*4 + (lane >> 4);
  const int tx = lane & 15;
  const __hip_bfloat16* hrow = hbuf + (size_t)r*T*4;
  for (int p = tx; p < 1022; p += 16){
    uint2 va = *(const uint2*)(hrow + (size_t)p*8);
    uint2 vb = *(const uint2*)(hrow + (size_t)p*8 + 4);
    float a0=blo(va.x),a1=bhi(va.x),a2=blo(va.y),a3=bhi(va.y);
    float b0=blo(vb.x),b1=bhi(vb.x),b2=blo(vb.y),b3=bhi(vb.y);
    atomicAdd(&ls [2*p    ], a0+a1+a2+a3);
    atomicAdd(&ls2[2*p    ], a0*a0+a1*a1+a2*a2+a3*a3);
    atomicAdd(&ls [2*p + 1], b0+b1+b2+b3);
    atomicAdd(&ls2[2*p + 1], b0*b0+b1*b1+b2*b2+b3*b3);
  }
  if (tx == 0){  // tail t = 2044
    uint2 va = *(const uint2*)(hrow + (size_t)2044*4);
    float a0=blo(va.x),a1=bhi(va.x),a2=blo(va.y),a3=bhi(va.y);
    atomicAdd(&ls [2044], a0+a1+a2+a3);
    atomicAdd(&ls2[2044], a0*a0+a1*a1+a2*a2+a3*a3);
  }
  __syncthreads();
  for (int i = threadIdx.x; i < T; i += 256){
    atomicAdd(&gsum[i],  ls[i]);
    atomicAdd(&gsum2[i], ls2[i]);
  }
}

// ---------------- K5: fuse bn2(h) + bn1(y1) -> flat bf16 (padded 8192) ----------
__global__ __launch_bounds__(256) void k_fuse(
    const __hip_bfloat16* __restrict__ hbuf, const float* __restrict__ y1,
    const float2* __restrict__ ab1, const float2* __restrict__ ab2,
    __hip_bfloat16* __restrict__ flat)
{
  const int idx = blockIdx.x*256 + threadIdx.x;   // 2048 rows * 1024 pairs
  const int r = idx >> 10;
  const int p = idx & 1023;
  unsigned w[4];
  #pragma unroll
  for (int hv = 0; hv < 2; hv++){
    const int t = 2*p + hv;
    float v0, v1, v2, v3;
    if (t < T){
      uint2 hh = *(const uint2*)(hbuf + ((size_t)r*T + t)*4);
      float4 yy = *(const float4*)(y1 + ((size_t)r*Tp + t)*4);
      float2 A1 = ab1[t];
      float2 A2 = ab2[t];
      v0 = fmaf(blo(hh.x), A2.x, A2.y) + fmaf(yy.x, A1.x, A1.y);
      v1 = fmaf(bhi(hh.x), A2.x, A2.y) + fmaf(yy.y, A1.x, A1.y);
      v2 = fmaf(blo(hh.y), A2.x, A2.y) + fmaf(yy.z, A1.x, A1.y);
      v3 = fmaf(bhi(hh.y), A2.x, A2.y) + fmaf(yy.w, A1.x, A1.y);
    } else { v0=v1=v2=v3=0.f; }
    w[hv*2+0] = packbf(v0, v1);
    w[hv*2+1] = packbf(v2, v3);
  }
  uint4 o4 = make_uint4(w[0], w[1], w[2], w[3]);
  *(uint4*)(flat + ((size_t)r*KFp + ((size_t)p << 3))) = o4;
}

// ---------------- K6: fp32 KxN -> bf16 NpxKp transpose (zero-padded) ------------
__global__ __launch_bounds__(256) void k_transpose(
    const float* __restrict__ src, __hip_bfloat16* __restrict__ dst,
    int K, int N, int Kp, int Np)
{
  __shared__ float tile[32][33];
  const int k0 = blockIdx.x*32, n0 = blockIdx.y*32;
  const int tx = threadIdx.x & 31, tyv = threadIdx.x >> 5;
  #pragma unroll
  for (int q = 0; q < 4; q++){
    int k = k0 + tyv + q*8, n = n0 + tx;
    tile[tyv + q*8][tx] = (k < K && n < N) ? src[(size_t)k*N + n] : 0.f;
  }
  __syncthreads();
  #pragma unroll
  for (int q = 0; q < 4; q++){
    int n = n0 + tyv + q*8, k = k0 + tx;
    dst[(size_t)n*Kp + k] = __float2bfloat16(tile[tx][tyv + q*8]);
  }
}

// ---------------- K7: bf16 MFMA GEMM (A row-major MxK, B as [n][k]) -------------
#define AS1 __attribute__((address_space(1)))
#define AS3 __attribute__((address_space(3)))
__global__ __launch_bounds__(256) void k_gemm(
    const __hip_bfloat16* __restrict__ A, int lda,
    const __hip_bfloat16* __restrict__ Bm, int ldb,
    int Klen, float* __restrict__ Cb, size_t csplit, int ldc,
    int nvalid, const float* __restrict__ bias, int epi)
{
  __shared__ __hip_bfloat16 As[4096];   // [128][32]
  __shared__ __hip_bfloat16 Bs[4096];   // [128][32]
  const int tid = threadIdx.x;
  const int lane = tid & 63;
  const int wv = tid >> 6;
  const int M0 = blockIdx.x * 128;
  const int N0 = blockIdx.y * 128;
  const int Kstart = blockIdx.z * Klen;
  float* C = Cb + (size_t)blockIdx.z * csplit;

  const int s0 = wv*64 + lane;
  const int arow = s0 >> 2, aseg = (s0 & 3) * 8;
  const __hip_bfloat16* gA0 = A  + (size_t)(M0 + arow)      * lda + Kstart + aseg;
  const __hip_bfloat16* gA1 = A  + (size_t)(M0 + arow + 64) * lda + Kstart + aseg;
  const __hip_bfloat16* gB0 = Bm + (size_t)(N0 + arow)      * ldb + Kstart + aseg;
  const __hip_bfloat16* gB1 = Bm + (size_t)(N0 + arow + 64) * ldb + Kstart + aseg;
  char* dA0 = (char*)As + wv*1024;
  char* dA1 = (char*)As + 4096 + wv*1024;
  char* dB0 = (char*)Bs + wv*1024;
  char* dB1 = (char*)Bs + 4096 + wv*1024;

  const int wm = (wv & 1) * 64;
  const int wn = (wv >> 1) * 64;
  const int lr = lane & 15;
  const int lk = lane >> 4;

  f32x4 acc[4][4] = {};

  for (int kk = 0; kk < Klen; kk += 32){
    __builtin_amdgcn_global_load_lds((const AS1 void*)gA0, (AS3 void*)dA0, 16, 0, 0);
    __builtin_amdgcn_global_load_lds((const AS1 void*)gA1, (AS3 void*)dA1, 16, 0, 0);
    __builtin_amdgcn_global_load_lds((const AS1 void*)gB0, (AS3 void*)dB0, 16, 0, 0);
    __builtin_amdgcn_global_load_lds((const AS1 void*)gB1, (AS3 void*)dB1, 16, 0, 0);
    gA0 += 32; gA1 += 32; gB0 += 32; gB1 += 32;
    __syncthreads();
    bf16x8 af[4], bfr[4];
    #pragma unroll
    for (int mi = 0; mi < 4; mi++)
      af[mi] = *(const bf16x8*)((char*)As + (wm + mi*16 + lr)*64 + lk*16);
    #pragma unroll
    for (int ni = 0; ni < 4; ni++)
      bfr[ni] = *(const bf16x8*)((char*)Bs + (wn + ni*16 + lr)*64 + lk*16);
    #pragma unroll
    for (int mi = 0; mi < 4; mi++)
      #pragma unroll
      for (int ni = 0; ni < 4; ni++)
        acc[mi][ni] = __builtin_amdgcn_mfma_f32_16x16x32_bf16(af[mi], bfr[ni], acc[mi][ni], 0, 0, 0);
    __syncthreads();
  }

  #pragma unroll
  for (int mi = 0; mi < 4; mi++){
    #pragma unroll
    for (int ni = 0; ni < 4; ni++){
      const int row = M0 + wm + mi*16 + lk*4;
      const int col = N0 + wn + ni*16 + lr;
      if (epi == 0){
        float* cp = C + (size_t)row*ldc + col;
        #pragma unroll
        for (int q = 0; q < 4; q++) cp[(size_t)q*ldc] = acc[mi][ni][q];
      } else if (col < nvalid){
        const float bz = bias[col];
        float* cp = C + (size_t)row*ldc + col;
        #pragma unroll
        for (int q = 0; q < 4; q++) cp[(size_t)q*ldc] = acc[mi][ni][q] + bz;
      }
    }
  }
}

// ---------------- K8: combine split-K partials + bias + gelu -> act bf16 --------
__global__ __launch_bounds__(256) void k_comb(
    const float* __restrict__ part, const float* __restrict__ b_fc1,
    __hip_bfloat16* __restrict__ act)
{
  const int idx = blockIdx.x*256 + threadIdx.x;   // 2048*128
  const int m = idx >> 7;
  const int n = (idx & 127) << 2;
  const size_t o = (size_t)m*HID + n;
  const size_t S = (size_t)2048*HID;
  float4 p0 = *(const float4*)(part + o);
  float4 p1 = *(const float4*)(part + S + o);
  float4 p2 = *(const float4*)(part + 2*S + o);
  float4 p3 = *(const float4*)(part + 3*S + o);
  float4 bz = *(const float4*)(b_fc1 + n);
  float v0 = gelu_f(p0.x+p1.x+p2.x+p3.x+bz.x);
  float v1 = gelu_f(p0.y+p1.y+p2.y+p3.y+bz.y);
  float v2 = gelu_f(p0.z+p1.z+p2.z+p3.z+bz.z);
  float v3 = gelu_f(p0.w+p1.w+p2.w+p3.w+bz.w);
  uint2 pk; pk.x = packbf(v0, v1); pk.y = packbf(v2, v3);
  *(uint2*)(act + o) = pk;
}

// ---------------- launch --------------------------------------------------------
extern "C" void kernel_launch(void* const* d_in, const int* in_sizes, int n_in,
                              void* d_out, int out_size, void* d_ws, size_t ws_size,
                              hipStream_t stream)
{
  (void)in_sizes; (void)n_in; (void)out_size; (void)ws_size;
  const float* x     = (const float*)d_in[0];
  const float* pe    = (const float*)d_in[1];
  const float* w_seg = (const float*)d_in[2];
  const float* b_seg = (const float*)d_in[3];
  const float* bn1_g = (const float*)d_in[4];
  const float* bn1_b = (const float*)d_in[5];
  const float* w_ih  = (const float*)d_in[6];
  const float* w_hh  = (const float*)d_in[7];
  const float* bn2_g = (const float*)d_in[8];
  const float* bn2_b = (const float*)d_in[9];
  const float* w_fc1 = (const float*)d_in[10];
  const float* b_fc1 = (const float*)d_in[11];
  const float* w_fc2 = (const float*)d_in[12];
  const float* b_fc2 = (const float*)d_in[13];
  float* out = (float*)d_out;

  char* ws = (char*)d_ws;
  float* y1            = (float*)(ws + OFF_Y1);
  __hip_bfloat16* hbuf = (__hip_bfloat16*)(ws + OFF_HBUF);
  __hip_bfloat16* flat = (__hip_bfloat16*)(ws + OFF_FLAT);
  __hip_bfloat16* w1t  = (__hip_bfloat16*)(ws + OFF_W1T);
  __hip_bfloat16* w2t  = (__hip_bfloat16*)(ws + OFF_W2T);
  float* part          = (float*)(ws + OFF_PART);
  __hip_bfloat16* act  = (__hip_bfloat16*)(ws + OFF_ACT);
  float* gs            = (float*)(ws + OFF_GS);
  float2* ab1          = (float2*)(ws + OFF_AB);
  float2* ab2          = ab1 + 2048;

  hipMemsetAsync(gs, 0, 4*2048*sizeof(float), stream);

  k_stageA<<<dim3(32,128), 256, 0, stream>>>(x, pe, w_seg, b_seg, y1, gs, gs + 2048);
  k_bnfin <<<8, 256, 0, stream>>>(gs, gs + 2048, bn1_g, bn1_b, ab1);
  k_lstm  <<<512, 64, 0, stream>>>(y1, ab1, w_ih, w_hh, hbuf);
  k_bn2red<<<128, 256, 0, stream>>>(hbuf, gs + 4096, gs + 6144);
  k_bnfin <<<8, 256, 0, stream>>>(gs + 4096, gs + 6144, bn2_g, bn2_b, ab2);
  k_transpose<<<dim3(256,16), 256, 0, stream>>>(w_fc1, w1t, 8180, 512, 8192, 512);
  k_transpose<<<dim3(16,24),  256, 0, stream>>>(w_fc2, w2t, 512, 720, 512, 768);
  k_fuse  <<<8192, 256, 0, stream>>>(hbuf, y1, ab1, ab2, flat);
  k_gemm  <<<dim3(16,4,4), 256, 0, stream>>>(flat, 8192, w1t, 8192, 2048,
                                             part, (size_t)2048*512, 512, 512, nullptr, 0);
  k_comb  <<<1024, 256, 0, stream>>>(part, b_fc1, act);
  k_gemm  <<<dim3(16,6,1), 256, 0, stream>>>(act, 512, w2t, 512, 512,
                                             out, 0, 720, 720, b_fc2, 1);
}